// Round 6
// baseline (716.771 us; speedup 1.0000x reference)
//
#include <hip/hip_runtime.h>

#define NPTS 32768
#define G 32
#define NCELL (G*G*G)          // 32768 cells per cloud
#define SSTR (NCELL + 1)
#define RANGE 4.5f
#define CELLW 0.28125f         // 9/32, exact in fp32

typedef unsigned int u32;

// Workspace layout:
//  [0K)     float4 sortedA[32768]   512KB   pred, counting-sorted by cell
//  [512K)   float4 sortedB[32768]   512KB   targ, counting-sorted by cell
//  [1024K)  u32    S[2][SSTR]       257KB   exclusive scan (+terminator NPTS)
//  [1344K)  u32    cursor[2][NCELL] 256KB   scatter cursors

__device__ __forceinline__ int cell_of(float v) {
    int c = (int)floorf((v + RANGE) * (G / (2.0f * RANGE)));
    return min(max(c, 0), G - 1);   // outliers clamp inward -> all bounds stay conservative
}
__device__ __forceinline__ float cell_lo(int i) {   // exact: i*(9/32) - 4.5
    return fmaf((float)i, CELLW, -RANGE);
}

// ---- Build: ONE plain dispatch, one 1024-thread block per cloud. ----
// LDS u16-packed histogram (64KB) -> shuffle scan -> S/cursor -> scatter.
__global__ __launch_bounds__(1024)
void build_sort(const float* __restrict__ pred, const float* __restrict__ targ,
                float4* __restrict__ sortedA, float4* __restrict__ sortedB,
                u32* __restrict__ S, u32* __restrict__ cursor, float* __restrict__ out) {
    __shared__ u32 hist[NCELL / 2];   // 2 u16 counts per word; max cell count << 65536
    __shared__ u32 wt[16];
    int cloud = blockIdx.x;
    const float* p = cloud ? targ : pred;
    float4* dst = cloud ? sortedB : sortedA;
    u32* s   = S + cloud * SSTR;
    u32* cur = cursor + cloud * NCELL;
    int t = threadIdx.x, lane = t & 63, wave = t >> 6;

    if (cloud == 0 && t == 0) *out = 0.0f;    // re-zeroed every graph replay

    #pragma unroll
    for (int k = 0; k < NCELL / 2 / 1024; ++k) hist[t + k * 1024] = 0;
    __syncthreads();

    // histogram: packed u16 add (no carry: per-cell count <= NPTS < 65536)
    #pragma unroll
    for (int k = 0; k < NPTS / 1024; ++k) {
        int i = t + k * 1024;
        float x = p[3*i], y = p[3*i+1], z = p[3*i+2];
        int c = (cell_of(z) * G + cell_of(y)) * G + cell_of(x);
        atomicAdd(&hist[c >> 1], 1u << ((c & 1) * 16));
    }
    __syncthreads();

    // scan: thread t owns words [16t,16t+16) == cells [32t,32t+32)
    u32 run = 0;
    #pragma unroll
    for (int k = 0; k < 16; ++k) {
        u32 w = hist[16 * t + k];
        run += (w & 0xffffu) + (w >> 16);
    }
    u32 inc = run;
    #pragma unroll
    for (int off = 1; off < 64; off <<= 1) {
        u32 nv = __shfl_up(inc, off, 64);
        if (lane >= off) inc += nv;
    }
    if (lane == 63) wt[wave] = inc;
    __syncthreads();
    if (t == 0) {
        u32 a = 0;
        #pragma unroll
        for (int w = 0; w < 16; ++w) { u32 v = wt[w]; wt[w] = a; a += v; }
    }
    __syncthreads();
    u32 tb = wt[wave] + (inc - run);          // global exclusive base for cell 32t
    #pragma unroll
    for (int k = 0; k < 16; ++k) {
        u32 w = hist[16 * t + k];
        u32 lo = w & 0xffffu, hi = w >> 16;
        int c = 32 * t + 2 * k;
        s[c] = tb;        cur[c] = tb;
        s[c+1] = tb + lo; cur[c+1] = tb + lo;
        tb += lo + hi;
    }
    if (t == 1023) s[NCELL] = NPTS;
    __threadfence();                          // cursor writes -> L2 before block atomics
    __syncthreads();

    // scatter into cell-sorted order
    #pragma unroll
    for (int k = 0; k < NPTS / 1024; ++k) {
        int i = t + k * 1024;
        float x = p[3*i], y = p[3*i+1], z = p[3*i+2];
        int c = (cell_of(z) * G + cell_of(y)) * G + cell_of(x);
        u32 pos = atomicAdd(&cur[c], 1u);
        dst[pos] = make_float4(x, y, z, 0.0f);
    }
}

// ---- Query: 8 lanes/query; 27-box as 9 x-runs (2 latency rounds); ----
// ---- stragglers (box bound fails) stream the whole cloud, pipelined. ----
__global__ __launch_bounds__(256, 8)
void query_min(const float4* __restrict__ sortedA, const float4* __restrict__ sortedB,
               const u32* __restrict__ Sall, float* __restrict__ out) {
    int tid = blockIdx.x * 256 + threadIdx.x;        // 0..524287
    int sub = tid & 7;
    int qi = tid >> 3;                               // 0..65535
    int cloud = qi >> 15, k = qi & (NPTS - 1);
    const float4* Q = cloud ? sortedB : sortedA;
    const float4* T = cloud ? sortedA : sortedB;
    const u32* s = Sall + (cloud ^ 1) * SSTR;        // other cloud's grid

    float4 q = Q[k];
    int cx = cell_of(q.x), cy = cell_of(q.y), cz = cell_of(q.z);
    int x0 = max(cx - 1, 0), x1 = min(cx + 1, G - 1);
    float best = 3.4e38f;

    // center-row + 8 neighbor-row descriptors: issued early, all independent
    int cbc = (cz * G + cy) * G;
    u32 cbeg = s[cbc + x0], cend = s[cbc + x1 + 1];
    u32 rb[9], re[9];
    #pragma unroll
    for (int i = 0; i < 9; ++i) {
        int dy = (i % 3) - 1, dz = (i / 3) - 1;
        int Y = cy + dy, Z = cz + dz;
        rb[i] = 0; re[i] = 0;
        if (i != 4 && (unsigned)Y < G && (unsigned)Z < G) {
            int cb = (Z * G + Y) * G;
            rb[i] = s[cb + x0]; re[i] = s[cb + x1 + 1];
        }
    }

    auto scan_seg = [&](u32 beg, u32 end) {
        for (u32 e = beg + sub; e < end; e += 8) {   // 8 lanes: 128B-coalesced iters
            float4 t = T[e];
            float dx = q.x - t.x, dy = q.y - t.y, dz = q.z - t.z;
            best = fminf(best, fmaf(dx, dx, fmaf(dy, dy, dz * dz)));
        }
    };
    auto group_min = [&]() {
        best = fminf(best, __shfl_xor(best, 1, 64));
        best = fminf(best, __shfl_xor(best, 2, 64));
        best = fminf(best, __shfl_xor(best, 4, 64));
    };

    // round 1: center row (contains own cell)
    scan_seg(cbeg, cend);
    group_min();

    // round 2: prune rows against post-center best ONCE, scan survivors.
    // Pruned row: mind2 >= best-at-prune >= final best -> exact.
    #pragma unroll
    for (int i = 0; i < 9; ++i) {
        if (i == 4) continue;
        int dy = (i % 3) - 1, dz = (i / 3) - 1;
        int Y = cy + dy, Z = cz + dz;
        if ((unsigned)Y >= G || (unsigned)Z >= G) continue;
        float ey = dy > 0 ? cell_lo(Y) - q.y : q.y - cell_lo(Y + 1);
        float ez = dz > 0 ? cell_lo(Z) - q.z : q.z - cell_lo(Z + 1);
        if (dy == 0) ey = 0.0f;
        if (dz == 0) ez = 0.0f;
        float mind2 = fmaf(ey, ey, ez * ez);
        if (mind2 < best) scan_seg(rb[i], re[i]);    // group-uniform branch
    }
    group_min();

    // box-completeness bound (domain-edge faces: nothing beyond, points clamp inward)
    float bd = 3.4e38f;
    if (cx - 1 > 0)     bd = fminf(bd, q.x - cell_lo(cx - 1));
    if (cx + 1 < G - 1) bd = fminf(bd, cell_lo(cx + 2) - q.x);
    if (cy - 1 > 0)     bd = fminf(bd, q.y - cell_lo(cy - 1));
    if (cy + 1 < G - 1) bd = fminf(bd, cell_lo(cy + 2) - q.y);
    if (cz - 1 > 0)     bd = fminf(bd, q.z - cell_lo(cz - 1));
    if (cz + 1 < G - 1) bd = fminf(bd, cell_lo(cz + 2) - q.z);

    if (best > bd * bd) {
        // straggler (~0.5-1% of queries, wave-clustered by sort order):
        // stream the WHOLE target cloud. 4096 independent float4 loads/lane,
        // unroll-4 keeps >=4 in flight -> latency pipelined, ~30us wall.
        // Unconditionally exact; replaces the serial shell walk.
        #pragma unroll 4
        for (u32 e = sub; e < NPTS; e += 8) {
            float4 t = T[e];
            float dx = q.x - t.x, dy = q.y - t.y, dz = q.z - t.z;
            best = fminf(best, fmaf(dx, dx, fmaf(dy, dy, dz * dz)));
        }
        group_min();
    }

    // fused mean: each query's best replicated on its 8 lanes -> weight 1/8
    float v = best * 0.125f;
    #pragma unroll
    for (int off = 1; off < 64; off <<= 1)
        v += __shfl_xor(v, off, 64);
    __shared__ float wsum[4];
    int lane = threadIdx.x & 63, wave = threadIdx.x >> 6;
    if (lane == 0) wsum[wave] = v;
    __syncthreads();
    if (threadIdx.x == 0)
        atomicAdd(out, (wsum[0] + wsum[1] + wsum[2] + wsum[3]) * (1.0f / NPTS));
}

extern "C" void kernel_launch(void* const* d_in, const int* in_sizes, int n_in,
                              void* d_out, int out_size, void* d_ws, size_t ws_size,
                              hipStream_t stream) {
    const float* pred = (const float*)d_in[0];
    const float* targ = (const float*)d_in[1];
    float* out = (float*)d_out;
    char* ws = (char*)d_ws;
    float4* sortedA = (float4*)(ws);
    float4* sortedB = (float4*)(ws + (512 << 10));
    u32* S      = (u32*)(ws + (1024 << 10));
    u32* cursor = (u32*)(ws + (1344 << 10));

    build_sort<<<2, 1024, 0, stream>>>(pred, targ, sortedA, sortedB, S, cursor, out);
    query_min <<<2048, 256, 0, stream>>>(sortedA, sortedB, S, out);
}

// Round 7
// 230.834 us; speedup vs baseline: 3.1051x; 3.1051x over previous
//
#include <hip/hip_runtime.h>

#define NPTS 32768
#define G 32
#define NCELL (G*G*G)          // 32768 cells per cloud
#define SSTR (NCELL + 1)
#define RANGE 4.5f
#define CELLW 0.28125f         // 9/32, exact in fp32

typedef unsigned int u32;

// Workspace layout:
//  [0K)     float4 sortedA[32768]   512KB   pred, counting-sorted by cell
//  [512K)   float4 sortedB[32768]   512KB   targ, counting-sorted by cell
//  [1024K)  u32    S[2][SSTR]       257KB   exclusive scan (+terminator NPTS)
//  [1344K)  u32    cnt[2][NCELL]    256KB   histogram (memset to 0)
//  [1600K)  u32    cursor[2][NCELL] 256KB   scatter cursors

__device__ __forceinline__ int cell_of(float v) {
    int c = (int)floorf((v + RANGE) * (G / (2.0f * RANGE)));
    return min(max(c, 0), G - 1);   // outliers clamp inward -> all bounds stay conservative
}
__device__ __forceinline__ float cell_lo(int i) {   // exact: i*(9/32) - 4.5
    return fmaf((float)i, CELLW, -RANGE);
}

// ---- Build stage 1: histogram, one point/thread, global atomics ----
__global__ __launch_bounds__(256)
void hist_k(const float* __restrict__ pred, const float* __restrict__ targ,
            u32* __restrict__ cnt, float* __restrict__ out) {
    int i = blockIdx.x * 256 + threadIdx.x;          // 0..65535
    if (i == 0) *out = 0.0f;                         // re-zeroed every replay
    int cloud = i >> 15, k = i & (NPTS - 1);
    const float* p = cloud ? targ : pred;
    float x = p[3*k], y = p[3*k+1], z = p[3*k+2];
    int c = (cell_of(z) * G + cell_of(y)) * G + cell_of(x);
    atomicAdd(&cnt[cloud * NCELL + c], 1u);
}

// ---- Build stage 2: per-cloud exclusive scan (1 block/cloud, 32 cells/thread) ----
__global__ __launch_bounds__(1024)
void scan_k(const u32* __restrict__ cnt, u32* __restrict__ S, u32* __restrict__ cursor) {
    int cloud = blockIdx.x;
    const u32* c = cnt + cloud * NCELL;
    u32* s   = S + cloud * SSTR;
    u32* cur = cursor + cloud * NCELL;
    __shared__ u32 wt[16];
    int t = threadIdx.x, lane = t & 63, wave = t >> 6;

    u32 loc[32], run = 0;
    #pragma unroll
    for (int k = 0; k < 32; ++k) { loc[k] = run; run += c[32 * t + k]; }
    u32 inc = run;
    #pragma unroll
    for (int off = 1; off < 64; off <<= 1) {
        u32 nv = __shfl_up(inc, off, 64);
        if (lane >= off) inc += nv;
    }
    if (lane == 63) wt[wave] = inc;
    __syncthreads();
    if (t == 0) {
        u32 a = 0;
        #pragma unroll
        for (int w = 0; w < 16; ++w) { u32 v = wt[w]; wt[w] = a; a += v; }
    }
    __syncthreads();
    u32 tb = wt[wave] + (inc - run);                 // exclusive base for cell 32t
    #pragma unroll
    for (int k = 0; k < 32; ++k) {
        u32 v = tb + loc[k];
        s[32 * t + k] = v; cur[32 * t + k] = v;
    }
    if (t == 1023) s[NCELL] = NPTS;
}

// ---- Build stage 3: scatter into cell-sorted order ----
__global__ __launch_bounds__(256)
void scatter_k(const float* __restrict__ pred, const float* __restrict__ targ,
               u32* __restrict__ cursor,
               float4* __restrict__ sortedA, float4* __restrict__ sortedB) {
    int i = blockIdx.x * 256 + threadIdx.x;
    int cloud = i >> 15, k = i & (NPTS - 1);
    const float* p = cloud ? targ : pred;
    float x = p[3*k], y = p[3*k+1], z = p[3*k+2];
    int c = (cell_of(z) * G + cell_of(y)) * G + cell_of(x);
    u32 pos = atomicAdd(&cursor[cloud * NCELL + c], 1u);
    (cloud ? sortedB : sortedA)[pos] = make_float4(x, y, z, 0.0f);
}

// distance from q to the boundary of box(R); domain-edge faces skipped
// (points clamp inward -> nothing lies beyond them): bound stays conservative.
__device__ __forceinline__ float box_bound(int cx, int cy, int cz, float4 q, int R) {
    float bd = 3.4e38f;
    if (cx - R > 0)     bd = fminf(bd, q.x - cell_lo(cx - R));
    if (cx + R < G - 1) bd = fminf(bd, cell_lo(cx + R + 1) - q.x);
    if (cy - R > 0)     bd = fminf(bd, q.y - cell_lo(cy - R));
    if (cy + R < G - 1) bd = fminf(bd, cell_lo(cy + R + 1) - q.y);
    if (cz - R > 0)     bd = fminf(bd, q.z - cell_lo(cz - R));
    if (cz + R < G - 1) bd = fminf(bd, cell_lo(cz + R + 1) - q.z);
    return bd;
}

// scan the whole box(R): per z-plane, dy-unrolled so the 2R+1 descriptor-pair
// loads issue together (one latency round per plane), then stream the x-runs.
template<int R>
__device__ __forceinline__ void scan_boxR(int cx, int cy, int cz, const u32* s,
                                          const float4* __restrict__ T,
                                          float4 q, int sub, float& best) {
    int xlo = max(cx - R, 0), xhi = min(cx + R, G - 1);
    for (int dz = -R; dz <= R; ++dz) {
        int Z = cz + dz;
        if ((unsigned)Z >= G) continue;
        #pragma unroll
        for (int dy = -R; dy <= R; ++dy) {
            int Y = cy + dy;
            if ((unsigned)Y >= G) continue;
            int cb = (Z * G + Y) * G;
            u32 b = s[cb + xlo], e = s[cb + xhi + 1];
            for (u32 t = b + sub; t < e; t += 8) {
                float4 p = T[t];
                float dx = q.x - p.x, dyy = q.y - p.y, dzz = q.z - p.z;
                best = fminf(best, fmaf(dx, dx, fmaf(dyy, dyy, dzz * dzz)));
            }
        }
    }
}

// ---- Query: 8 lanes/query; 27-box (2 latency rounds); tiered box(4)/box(9)
// ---- fallback for the ~3% sparse tail; whole-cloud brute adversarial-only.
__global__ __launch_bounds__(256, 8)
void query_min(const float4* __restrict__ sortedA, const float4* __restrict__ sortedB,
               const u32* __restrict__ Sall, float* __restrict__ out) {
    int tid = blockIdx.x * 256 + threadIdx.x;        // 0..524287
    int sub = tid & 7;
    int qi = tid >> 3;                               // 0..65535
    int cloud = qi >> 15, k = qi & (NPTS - 1);
    const float4* Q = cloud ? sortedB : sortedA;
    const float4* T = cloud ? sortedA : sortedB;
    const u32* s = Sall + (cloud ^ 1) * SSTR;        // other cloud's grid

    float4 q = Q[k];
    int cx = cell_of(q.x), cy = cell_of(q.y), cz = cell_of(q.z);
    int x0 = max(cx - 1, 0), x1 = min(cx + 1, G - 1);
    float best = 3.4e38f;

    // center-row + 8 neighbor-row descriptors: issued early, all independent
    int cbc = (cz * G + cy) * G;
    u32 cbeg = s[cbc + x0], cend = s[cbc + x1 + 1];
    u32 rb[9], re[9];
    #pragma unroll
    for (int i = 0; i < 9; ++i) {
        int dy = (i % 3) - 1, dz = (i / 3) - 1;
        int Y = cy + dy, Z = cz + dz;
        rb[i] = 0; re[i] = 0;
        if (i != 4 && (unsigned)Y < G && (unsigned)Z < G) {
            int cb = (Z * G + Y) * G;
            rb[i] = s[cb + x0]; re[i] = s[cb + x1 + 1];
        }
    }

    auto scan_seg = [&](u32 beg, u32 end) {
        for (u32 e = beg + sub; e < end; e += 8) {   // 8 lanes: 128B-coalesced iters
            float4 t = T[e];
            float dx = q.x - t.x, dy = q.y - t.y, dz = q.z - t.z;
            best = fminf(best, fmaf(dx, dx, fmaf(dy, dy, dz * dz)));
        }
    };
    auto group_min = [&]() {
        best = fminf(best, __shfl_xor(best, 1, 64));
        best = fminf(best, __shfl_xor(best, 2, 64));
        best = fminf(best, __shfl_xor(best, 4, 64));
    };

    // round 1: center row (contains own cell)
    scan_seg(cbeg, cend);
    group_min();

    // round 2: prune rows against post-center best ONCE, scan survivors.
    // Pruned row: mind2 >= best-at-prune >= final best -> exact.
    #pragma unroll
    for (int i = 0; i < 9; ++i) {
        if (i == 4) continue;
        int dy = (i % 3) - 1, dz = (i / 3) - 1;
        int Y = cy + dy, Z = cz + dz;
        if ((unsigned)Y >= G || (unsigned)Z >= G) continue;
        float ey = dy > 0 ? cell_lo(Y) - q.y : q.y - cell_lo(Y + 1);
        float ez = dz > 0 ? cell_lo(Z) - q.z : q.z - cell_lo(Z + 1);
        if (dy == 0) ey = 0.0f;
        if (dz == 0) ez = 0.0f;
        float mind2 = fmaf(ey, ey, ez * ez);
        if (mind2 < best) scan_seg(rb[i], re[i]);    // group-uniform branch
    }
    group_min();

    // tiered fallback: each tier rescans a superset box (idempotent min),
    // then re-checks the exact outside-the-box bound. ~3% enter tier 2,
    // ~0.06% tier 3, brute is adversarial-only.
    float bd = box_bound(cx, cy, cz, q, 1);
    if (best > bd * bd) {
        scan_boxR<4>(cx, cy, cz, s, T, q, sub, best);
        group_min();
        float bd4 = box_bound(cx, cy, cz, q, 4);
        if (best > bd4 * bd4) {
            scan_boxR<9>(cx, cy, cz, s, T, q, sub, best);
            group_min();
            float bd9 = box_bound(cx, cy, cz, q, 9);
            if (best > bd9 * bd9) {
                for (u32 e = sub; e < NPTS; e += 8) {
                    float4 t = T[e];
                    float dx = q.x - t.x, dy = q.y - t.y, dz = q.z - t.z;
                    best = fminf(best, fmaf(dx, dx, fmaf(dy, dy, dz * dz)));
                }
                group_min();
            }
        }
    }

    // fused mean: each query's best replicated on its 8 lanes -> weight 1/8
    float v = best * 0.125f;
    #pragma unroll
    for (int off = 1; off < 64; off <<= 1)
        v += __shfl_xor(v, off, 64);
    __shared__ float wsum[4];
    int lane = threadIdx.x & 63, wave = threadIdx.x >> 6;
    if (lane == 0) wsum[wave] = v;
    __syncthreads();
    if (threadIdx.x == 0)
        atomicAdd(out, (wsum[0] + wsum[1] + wsum[2] + wsum[3]) * (1.0f / NPTS));
}

extern "C" void kernel_launch(void* const* d_in, const int* in_sizes, int n_in,
                              void* d_out, int out_size, void* d_ws, size_t ws_size,
                              hipStream_t stream) {
    const float* pred = (const float*)d_in[0];
    const float* targ = (const float*)d_in[1];
    float* out = (float*)d_out;
    char* ws = (char*)d_ws;
    float4* sortedA = (float4*)(ws);
    float4* sortedB = (float4*)(ws + (512 << 10));
    u32* S      = (u32*)(ws + (1024 << 10));
    u32* cnt    = (u32*)(ws + (1344 << 10));
    u32* cursor = (u32*)(ws + (1600 << 10));

    hipMemsetAsync(cnt, 0, 2 * NCELL * sizeof(u32), stream);
    hist_k   <<<256, 256, 0, stream>>>(pred, targ, cnt, out);
    scan_k   <<<2, 1024, 0, stream>>>(cnt, S, cursor);
    scatter_k<<<256, 256, 0, stream>>>(pred, targ, cursor, sortedA, sortedB);
    query_min<<<2048, 256, 0, stream>>>(sortedA, sortedB, S, out);
}